// Round 7
// baseline (538.467 us; speedup 1.0000x reference)
//
#include <hip/hip_runtime.h>
#include <hip/hip_bf16.h>
#include <math.h>

// B=32, L=2048, D_Q=D_V=1024, UNITS=512
#define NB 32
#define LL 2048
#define DV 1024
#define NU 512
#define NM (NB * LL)

typedef __attribute__((ext_vector_type(8))) short short8;
typedef __attribute__((ext_vector_type(4))) float f32x4;

#define GLL16(g, l)                                                            \
  __builtin_amdgcn_global_load_lds(                                            \
      (const __attribute__((address_space(1))) void*)(g),                      \
      (__attribute__((address_space(3))) void*)(l), 16, 0, 0)

__device__ __forceinline__ float fast_tanh(float x) {
  x = fminf(fmaxf(x, -15.f), 15.f);
  float e = __expf(2.f * x);
  return (e - 1.f) / (e + 1.f);
}

// ---------------------------------------------------------------------------
// prep: blocks 0..63 pack Wv -> bf16 (swizzled layout); blocks 64..95 compute
// h[b,u] = q@Wh + biases + log(1+ts)*Wp0 + log(1+masksum)*Wp2.
__global__ __launch_bounds__(256) void prep_kernel(
    const float* __restrict__ Wv, __hip_bfloat16* __restrict__ wvpk,
    const float* __restrict__ q, const float* __restrict__ Wh,
    const float* __restrict__ bh, const float* __restrict__ bv,
    const float* __restrict__ bp, const float* __restrict__ bm,
    const float* __restrict__ Wp, const int* __restrict__ ts,
    const float* __restrict__ mask, float* __restrict__ h) {
  if (blockIdx.x < 64) {
    // ---- wvpack: register transpose, coalesced reads.
    int t = blockIdx.x * 256 + threadIdx.x;  // 16384 threads
    int u4 = t & 127;
    int kg = t >> 7;
    int k0 = kg * 8;
    int kt = kg >> 2;
    int qd = kg & 3;
    float4 f[8];
#pragma unroll
    for (int j = 0; j < 8; j++)
      f[j] = *(const float4*)(Wv + (size_t)(k0 + j) * NU + u4 * 4);
#pragma unroll
    for (int e = 0; e < 4; e++) {
      int u = u4 * 4 + e;
      int nt = u >> 8, n = u & 255;
      int c = qd ^ ((n >> 1) & 3);
      int idx = nt * 32768 + kt * 1024 + n * 4 + c;
      const float* fe = (const float*)&f[0] + e;
      union {
        __hip_bfloat162 h2[4];
        int4 v;
      } pk;
#pragma unroll
      for (int m = 0; m < 4; m++)
        pk.h2[m] =
            __float22bfloat162_rn(make_float2(fe[(2 * m) * 4], fe[(2 * m + 1) * 4]));
      ((int4*)wvpk)[idx] = pk.v;
    }
    return;
  }
  // ---- h part
  int idx2 = blockIdx.x - 64;
  int u0 = (idx2 & 7) * 64;
  int bq = idx2 >> 3;
  int tid = threadIdx.x;

  __shared__ float qsL[8][1024];  // 32 KB
  __shared__ float cnt[8], lgl[8];

  {
    int g = tid & 31, bl = tid >> 5;
    const float4* mrow =
        (const float4*)(mask + (size_t)(bq * 8 + bl) * LL) + g * 16;
    float c = 0.f;
#pragma unroll
    for (int j = 0; j < 16; j++) {
      float4 m = mrow[j];
      c += (m.x == 0.f ? 1.f : 0.f) + (m.y == 0.f ? 1.f : 0.f) +
           (m.z == 0.f ? 1.f : 0.f) + (m.w == 0.f ? 1.f : 0.f);
    }
#pragma unroll
    for (int o = 16; o >= 1; o >>= 1) c += __shfl_xor(c, o, 64);
    if (g == 0) cnt[bl] = c;
  }
  __syncthreads();
  if (tid < 8) lgl[tid] = logf(1.f + cnt[tid]);

#pragma unroll
  for (int j = 0; j < 8; j++) {
    int f = j * 256 + tid;
    int bl = f >> 8, k4 = f & 255;
    *(float4*)&qsL[bl][k4 * 4] =
        *(const float4*)(q + (size_t)(bq * 8 + bl) * 1024 + k4 * 4);
  }
  __syncthreads();

  int u = tid & 63, bsub = tid >> 6;
  int b0 = bq * 8 + bsub * 2, b1 = b0 + 1;
  float a0e = 0.f, a0o = 0.f, a1e = 0.f, a1o = 0.f;
#pragma unroll 16
  for (int k = 0; k < 1024; k += 2) {
    float w0 = Wh[(size_t)k * NU + u0 + u];
    float w1 = Wh[(size_t)(k + 1) * NU + u0 + u];
    a0e += w0 * qsL[bsub * 2][k];
    a1e += w0 * qsL[bsub * 2 + 1][k];
    a0o += w1 * qsL[bsub * 2][k + 1];
    a1o += w1 * qsL[bsub * 2 + 1][k + 1];
  }
  float acc0 = a0e + a0o, acc1 = a1e + a1o;

  int uu = u0 + u;
  float lt = logf(1.0f + (float)ts[0]);
  float bias = bh[uu] + bv[uu] + bp[uu] + bm[uu] + lt * Wp[uu];
  float wp2 = Wp[2 * NU + uu];
  h[b0 * NU + uu] = acc0 + bias + lgl[bsub * 2] * wp2;
  h[b1 * NU + uu] = acc1 + bias + lgl[bsub * 2 + 1] * wp2;
}

// ---------------------------------------------------------------------------
// Score, MERGED-ntile: one block computes ALL 512 u-columns for its 128 rows
// -> values read ONCE (256 MB not 512 MB through-cache), and the block emits
// FINAL scores (no partial buffer). 512 thr = 8 waves (2 row x 4 col), wave
// tile 64x128, acc[4][8] (~128 VGPR acc). LDS ~97.5 KB -> 1 block/CU.
// Schedule: EXACT R4/R6-proven double-buffered __syncthreads loop.
// Launched twice (mbase 0/256) so per-dispatch dur drops to ~half, unmasking
// any hidden >80us kernel in the top-5 profile view.
__global__ __launch_bounds__(512, 2) void score_kernel(
    const float* __restrict__ values, const __hip_bfloat16* __restrict__ wvpk,
    const float* __restrict__ h, const float* __restrict__ Wp,
    const float* __restrict__ Wm, const float* __restrict__ vw,
    const float* __restrict__ prev, float* __restrict__ score, int mbase) {
  int mtile = mbase + blockIdx.x;       // 0..511
  int tid = threadIdx.x;
  int lane = tid & 63, wid = tid >> 6;  // wid 0..7
  int wr = wid >> 2, wc = wid & 3;      // 2 x 4 wave grid
  int col = lane & 15, quad = lane >> 4;
  int b = mtile >> 4;
  int l0 = (mtile & 15) << 7;
  int rowbase = mtile << 7;

  __shared__ __align__(16) char AsB[2][8192];   // 128 rows x 64B, swizzled
  __shared__ __align__(16) char BsB[2][32768];  // 512 cols x 64B, swizzled
  __shared__ float hL[512], wp1L[512], vwL[512], wmL[5][512];
  __shared__ float loglS[128], prevs[132], scoreAcc[128];

  {
    hL[tid] = h[b * NU + tid];
    wp1L[tid] = Wp[NU + tid];
    vwL[tid] = vw[tid];
#pragma unroll
    for (int j = 0; j < 5; j++) wmL[j][tid] = Wm[j * NU + tid];
  }
  if (tid < 128) {
    loglS[tid] = __logf(2.0f + (float)(l0 + tid));
    scoreAcc[tid] = 0.f;
  }
  if (tid < 132) {
    int li = l0 - 2 + tid;
    prevs[tid] = (li >= 0 && li < LL) ? prev[(size_t)b * LL + li] : 0.f;
  }

  f32x4 acc[4][8];
  f32x4 zero4 = {0.f, 0.f, 0.f, 0.f};
#pragma unroll
  for (int i = 0; i < 4; i++)
#pragma unroll
    for (int j = 0; j < 8; j++) acc[i][j] = zero4;

  // A staging: 512 thr, 4 thr/row; thread covers 8 k (one 16B bf16 chunk).
  int row = tid >> 2, h0 = tid & 3;
  const float* abase = values + (size_t)(rowbase + row) * DV + h0 * 8;
  int s_sw = (row >> 1) & 3;
  int aoff = row * 64 + ((h0 ^ s_sw) * 16);
  const char* bbase = (const char*)wvpk;  // nt0 at 0, nt1 at +512KB
  int boff = tid * 16;                    // [0, 8192)

  float4 preA[2][2];  // 2-deep A prefetch, 8 floats per kt

#define CVT_STORE(SLOT, DSTBUF)                                                \
  {                                                                            \
    float4 f0 = preA[SLOT][0], f1 = preA[SLOT][1];                             \
    union {                                                                    \
      __hip_bfloat162 h2[4];                                                   \
      int4 v;                                                                  \
    } pk;                                                                      \
    pk.h2[0] = __float22bfloat162_rn(make_float2(f0.x, f0.y));                 \
    pk.h2[1] = __float22bfloat162_rn(make_float2(f0.z, f0.w));                 \
    pk.h2[2] = __float22bfloat162_rn(make_float2(f1.x, f1.y));                 \
    pk.h2[3] = __float22bfloat162_rn(make_float2(f1.z, f1.w));                 \
    *(int4*)(AsB[DSTBUF] + aoff) = pk.v;                                       \
  }

#define STAGE_B(KT, DSTBUF)                                                    \
  {                                                                            \
    const char* s0 = bbase + (size_t)(KT) * 16384;                             \
    const char* s1 = bbase + 524288 + (size_t)(KT) * 16384;                    \
    GLL16(s0 + boff, BsB[DSTBUF] + boff);                                      \
    GLL16(s0 + boff + 8192, BsB[DSTBUF] + boff + 8192);                        \
    GLL16(s1 + boff, BsB[DSTBUF] + 16384 + boff);                              \
    GLL16(s1 + boff + 8192, BsB[DSTBUF] + 24576 + boff);                       \
  }

  // Prologue: preA <- tiles 0,1; stage B(0)+A(0) into buf 0; preA[0] <- tile 2.
  {
#pragma unroll
    for (int d = 0; d < 2; d++) {
      preA[d][0] = *(const float4*)(abase + d * 32);
      preA[d][1] = *(const float4*)(abase + d * 32 + 4);
    }
    STAGE_B(0, 0);
    CVT_STORE(0, 0);
    preA[0][0] = *(const float4*)(abase + 2 * 32);
    preA[0][1] = *(const float4*)(abase + 2 * 32 + 4);
    __syncthreads();
  }

// Invariant entering KT (compute buf CBUF=KT&1):
//   slot[(KT+1)&1] holds A tile KT+1; slot[KT&1] holds A tile KT+2.
#define KSTEP(KT, CBUF, OSLOT, DO_STAGE, DO_RELOAD)                            \
  {                                                                            \
    if (DO_STAGE) {                                                            \
      STAGE_B((KT) + 1, (CBUF) ^ 1);                                           \
      CVT_STORE(OSLOT, (CBUF) ^ 1);                                            \
      if (DO_RELOAD) {                                                         \
        preA[OSLOT][0] = *(const float4*)(abase + ((KT) + 3) * 32);            \
        preA[OSLOT][1] = *(const float4*)(abase + ((KT) + 3) * 32 + 4);        \
      }                                                                        \
    }                                                                          \
    short8 aF[4];                                                              \
    _Pragma("unroll") for (int t = 0; t < 4; t++) {                            \
      int m = wr * 64 + t * 16 + col;                                          \
      aF[t] = *(const short8*)(AsB[CBUF] + m * 64 +                            \
                               ((quad ^ ((m >> 1) & 3)) * 16));                \
    }                                                                          \
    _Pragma("unroll") for (int tc = 0; tc < 8; tc++) {                         \
      int n = wc * 128 + tc * 16 + col;                                        \
      short8 bF =                                                              \
          *(const short8*)(BsB[CBUF] + n * 64 + ((quad ^ ((n >> 1) & 3)) * 16)); \
      _Pragma("unroll") for (int tr = 0; tr < 4; tr++) acc[tr][tc] =           \
          __builtin_amdgcn_mfma_f32_16x16x32_bf16(aF[tr], bF, acc[tr][tc], 0,  \
                                                  0, 0);                       \
    }                                                                          \
    __syncthreads();                                                           \
  }

  for (int kto = 0; kto < 14; kto++) {
    KSTEP(2 * kto, 0, 1, 1, 1);
    KSTEP(2 * kto + 1, 1, 0, 1, 1);
  }
  KSTEP(28, 0, 1, 1, 1);  // stage 29, reload slot1 <- 31
  KSTEP(29, 1, 0, 1, 0);  // stage 30
  KSTEP(30, 0, 1, 1, 0);  // stage 31
  KSTEP(31, 1, 0, 0, 0);  // compute only
#undef KSTEP
#undef STAGE_B
#undef CVT_STORE

  // Epilogue: full-u reduction in-block -> final scores.
  int rb = wr * 64;
#pragma unroll
  for (int tr = 0; tr < 4; tr++) {
    float ps[4] = {0.f, 0.f, 0.f, 0.f};
#pragma unroll
    for (int tc = 0; tc < 8; tc++) {
      int uc = wc * 128 + tc * 16 + col;
      float hh = hL[uc], wp1 = wp1L[uc], vv = vwL[uc];
      float m0 = wmL[0][uc], m1 = wmL[1][uc], m2 = wmL[2][uc],
            m3 = wmL[3][uc], m4 = wmL[4][uc];
      int r0 = rb + tr * 16 + quad * 4;
#pragma unroll
      for (int i = 0; i < 4; i++) {
        int r = r0 + i;
        float e = hh + loglS[r] * wp1 + prevs[r] * m0 + prevs[r + 1] * m1 +
                  prevs[r + 2] * m2 + prevs[r + 3] * m3 + prevs[r + 4] * m4;
        float sv = acc[tr][tc][i] + e;
        ps[i] += fast_tanh(sv) * vv;
      }
    }
#pragma unroll
    for (int i = 0; i < 4; i++) {
      float v = ps[i];
      v += __shfl_xor(v, 1, 64);
      v += __shfl_xor(v, 2, 64);
      v += __shfl_xor(v, 4, 64);
      v += __shfl_xor(v, 8, 64);
      if (col == 0) atomicAdd(&scoreAcc[rb + tr * 16 + quad * 4 + i], v);
    }
  }
  __syncthreads();
  if (tid < 128) score[rowbase + tid] = scoreAcc[tid];
}

// ---------------------------------------------------------------------------
// post: fused softmax + ctx, reading final scores directly.
__global__ __launch_bounds__(1024) void post_kernel(
    const float* __restrict__ score, const float* __restrict__ mask,
    const float* __restrict__ values, float* __restrict__ aw,
    float* __restrict__ out) {
  int b = blockIdx.x >> 3, chunk = blockIdx.x & 7;
  int tid = threadIdx.x;
  int lane = tid & 63, wid = tid >> 6;  // 16 waves
  __shared__ float wmx[16], wsm[16];
  __shared__ float awL[256];
  __shared__ f32x4 red[4][256];

  size_t base = (size_t)b * LL;
  float s1, s2;
  {
    size_t l1 = base + tid, l2 = base + tid + 1024;
    s1 = score[l1] + mask[l1] * -1.0e9f;
    s2 = score[l2] + mask[l2] * -1.0e9f;
  }
  float mx = fmaxf(s1, s2);
#pragma unroll
  for (int o = 32; o >= 1; o >>= 1) mx = fmaxf(mx, __shfl_xor(mx, o, 64));
  if (lane == 0) wmx[wid] = mx;
  __syncthreads();
  mx = wmx[0];
#pragma unroll
  for (int j = 1; j < 16; j++) mx = fmaxf(mx, wmx[j]);
  float e = __expf(s1 - mx) + __expf(s2 - mx);
#pragma unroll
  for (int o = 32; o >= 1; o >>= 1) e += __shfl_xor(e, o, 64);
  if (lane == 0) wsm[wid] = e;
  __syncthreads();
  float sum = 0.f;
#pragma unroll
  for (int j = 0; j < 16; j++) sum += wsm[j];
  float inv = 1.0f / sum;

  int l0 = chunk * 256;
  if (tid < 256) {
    size_t l = base + l0 + tid;
    float s = score[l] + mask[l] * -1.0e9f;
    float a = __expf(s - mx) * inv;
    aw[l] = a;
    awL[tid] = a;
  }
  __syncthreads();

  int s = tid & 255, rg = tid >> 8;
  const float4* vbase =
      (const float4*)(values + ((size_t)b * LL + l0 + rg * 64) * DV) + s;
  const float* awr = awL + rg * 64;
  float4 acc = make_float4(0.f, 0.f, 0.f, 0.f);
  for (int i0 = 0; i0 < 64; i0 += 8) {
    float4 v[8];
#pragma unroll
    for (int j = 0; j < 8; j++) v[j] = vbase[(size_t)(i0 + j) * 256];
#pragma unroll
    for (int j = 0; j < 8; j++) {
      float w = awr[i0 + j];
      acc.x += w * v[j].x;
      acc.y += w * v[j].y;
      acc.z += w * v[j].z;
      acc.w += w * v[j].w;
    }
  }
  f32x4 a4 = {acc.x, acc.y, acc.z, acc.w};
  red[rg][s] = a4;
  __syncthreads();
  if (tid < 256) {
    f32x4 r = red[0][s];
    f32x4 r1 = red[1][s], r2 = red[2][s], r3 = red[3][s];
    r += r1;
    r += r2;
    r += r3;
    float* o = out + (size_t)b * DV + s * 4;
    atomicAdd(o + 0, r[0]);
    atomicAdd(o + 1, r[1]);
    atomicAdd(o + 2, r[2]);
    atomicAdd(o + 3, r[3]);
  }
}

// ---------------------------------------------------------------------------
extern "C" void kernel_launch(void* const* d_in, const int* in_sizes, int n_in,
                              void* d_out, int out_size, void* d_ws,
                              size_t ws_size, hipStream_t stream) {
  const float* query = (const float*)d_in[0];
  const float* values = (const float*)d_in[1];
  const float* mask = (const float*)d_in[2];
  const float* prev = (const float*)d_in[3];
  const int* ts = (const int*)d_in[4];
  const float* Wh = (const float*)d_in[5];
  const float* bh = (const float*)d_in[6];
  const float* Wv = (const float*)d_in[7];
  const float* bv = (const float*)d_in[8];
  const float* Wp = (const float*)d_in[9];
  const float* bp = (const float*)d_in[10];
  const float* Wm = (const float*)d_in[11];
  const float* bm = (const float*)d_in[12];
  const float* vw = (const float*)d_in[13];
  // d_in[14] = vb: cancels under softmax.

  float* out = (float*)d_out;   // [0,32768) ctx, [32768,98304) aw
  float* ws = (float*)d_ws;
  float* h = ws + 1024;                  // 16384 f
  float* score = ws + 32768;             // 65536 f
  __hip_bfloat16* wvpk =
      (__hip_bfloat16*)((char*)d_ws + (size_t)163840 * 4);  // 1 MB
  float* aw = out + 32768;

  hipMemsetAsync(d_out, 0, 32768 * sizeof(float), stream);  // ctx accumulator
  prep_kernel<<<96, 256, 0, stream>>>(Wv, wvpk, query, Wh, bh, bv, bp, bm, Wp,
                                      ts, mask, h);
  score_kernel<<<256, 512, 0, stream>>>(values, wvpk, h, Wp, Wm, vw, prev,
                                        score, 0);
  score_kernel<<<256, 512, 0, stream>>>(values, wvpk, h, Wp, Wm, vw, prev,
                                        score, 256);
  post_kernel<<<256, 1024, 0, stream>>>(score, mask, values, aw, out);
}